// Round 1
// baseline (897.564 us; speedup 1.0000x reference)
//
#include <hip/hip_runtime.h>
#include <hip/hip_bf16.h>

// MultiExpertLoRALinear on MI355X.
// Strategy: fold LoRA (rank-8 x 4 experts = 32 cols) + router-weighted combo into
// the K-dim of the base GEMM. One fp16 MFMA GEMM [M=8192, N=4096, Kp=4160] does
// everything; epilogue adds bias.
// Pipeline: router_c (c = alpha*SCALING*z, fp32) -> convert_w (W|Bcat -> fp16)
//           -> convert_x (x|c -> fp16) -> gemm (16x16x32 f16 MFMA, 128x128 tile,
//           BK=64, global_load_lds + XOR-swizzled LDS, conflict-free ds_read_b128).

typedef _Float16 f16x8 __attribute__((ext_vector_type(8)));
typedef _Float16 f16x4 __attribute__((ext_vector_type(4)));
typedef float    f32x4 __attribute__((ext_vector_type(4)));

constexpr int H  = 4096;   // hidden dim (K of base GEMM)
constexpr int O  = 4096;   // output features (N)
constexpr int KP = 4160;   // 4096 + 32 (lora/router cols) + 32 zero pad -> /64 = 65 steps
constexpr int EA = 4;      // active experts
constexpr float SCALING_F = 2.0f;  // alpha/rank = 16/8

typedef const __attribute__((address_space(1))) void gvoid;
typedef __attribute__((address_space(3))) void svoid;

__device__ inline void gload16(const void* g, void* s) {
  __builtin_amdgcn_global_load_lds((gvoid*)g, (svoid*)s, 16, 0, 0);
}

// ---------------------------------------------------------------------------
// Kernel 1: per-token router logits + z dots -> c[t][32] = alpha_e*SCALING*z
// 36 dot products of length 4096 per token (rows 0..31: lora_A[ae][r],
// rows 32..35: router_W[ae]). Block = 32 tokens, k-chunks of 128 staged in LDS.
// ---------------------------------------------------------------------------
__global__ __launch_bounds__(256) void router_c_kernel(
    const float* __restrict__ x, const float* __restrict__ lora_A,
    const float* __restrict__ router_W, const float* __restrict__ router_b,
    const float* __restrict__ prior, const int* __restrict__ active,
    float* __restrict__ c) {
  constexpr int G = 32, KC = 128;
  __shared__ float xs[G][132];   // +4 pad: 16B-aligned rows, spreads banks
  __shared__ float vs[36][KC];
  const int tid = threadIdx.x;
  const long t0 = (long)blockIdx.x * G;
  const int tok = tid & 31;
  const int jg  = tid >> 5;      // 0..7; this thread owns j = jg + 8*i, i<5 (j<36)
  int ae[EA];
#pragma unroll
  for (int e = 0; e < EA; ++e) ae[e] = active[e];

  float acc[5] = {0.f, 0.f, 0.f, 0.f, 0.f};
  for (int k0 = 0; k0 < H; k0 += KC) {
    __syncthreads();
    // stage x chunk: 32 rows x 128 -> 1024 float4
#pragma unroll
    for (int i = 0; i < 4; ++i) {
      int v = tid + 256 * i;
      int tk = v >> 5, k4 = (v & 31) * 4;
      *(float4*)&xs[tk][k4] = *(const float4*)(x + (t0 + tk) * H + k0 + k4);
    }
    // stage V chunk: 36 rows x 128 -> 1152 float4
#pragma unroll
    for (int i = 0; i < 5; ++i) {
      int v = tid + 256 * i;
      if (v < 36 * 32) {
        int row = v >> 5, k4 = (v & 31) * 4;
        const float* vp = (row < 32)
            ? lora_A + (size_t)(ae[row >> 3] * 8 + (row & 7)) * H
            : router_W + (size_t)ae[row - 32] * H;
        *(float4*)&vs[row][k4] = *(const float4*)(vp + k0 + k4);
      }
    }
    __syncthreads();
    for (int k4 = 0; k4 < KC; k4 += 4) {
      float4 xv = *(const float4*)&xs[tok][k4];
#pragma unroll
      for (int i = 0; i < 5; ++i) {
        int j = jg + 8 * i;
        if (j < 36) {
          float4 vv = *(const float4*)&vs[j][k4];
          acc[i] += xv.x * vv.x + xv.y * vv.y + xv.z * vv.z + xv.w * vv.w;
        }
      }
    }
  }
  __syncthreads();
  float* res = &xs[0][0];  // reuse as [32][40]
#pragma unroll
  for (int i = 0; i < 5; ++i) {
    int j = jg + 8 * i;
    if (j < 36) res[tok * 40 + j] = acc[i];
  }
  __syncthreads();
  if (tid < 32) {
    float le[EA], mx = -1e30f;
#pragma unroll
    for (int e = 0; e < EA; ++e) {
      float lg = res[tid * 40 + 32 + e] + router_b[ae[e]];
      le[e] = logf(prior[ae[e]] + 1e-12f) + lg;   // GAMMA = 1
      mx = fmaxf(mx, le[e]);
    }
    float s = 0.f, al[EA];
#pragma unroll
    for (int e = 0; e < EA; ++e) { al[e] = expf(le[e] - mx); s += al[e]; }
    const float inv = SCALING_F / s;
#pragma unroll
    for (int e = 0; e < EA; ++e) {
      float a = al[e] * inv;
#pragma unroll
      for (int r = 0; r < 8; ++r)
        c[(t0 + tid) * 32 + e * 8 + r] = a * res[tid * 40 + e * 8 + r];
    }
  }
}

// ---------------------------------------------------------------------------
// Kernel 2: wh[o][KP] fp16 = [ W_base[o][0..4095] | Bcat[j][o] (j=e*8+r) | 0 ]
// ---------------------------------------------------------------------------
__global__ __launch_bounds__(256) void convert_w_kernel(
    const float* __restrict__ W, const float* __restrict__ lora_B,
    const int* __restrict__ active, _Float16* __restrict__ wh) {
  const int g = blockIdx.x * 256 + threadIdx.x;  // O * (KP/8) = 4096*520 groups
  const int o = g / 520;
  const int k = (g % 520) * 8;
  float v[8];
  if (k < H) {
    const float* s = W + (size_t)o * H + k;
    float4 a = *(const float4*)s, b = *(const float4*)(s + 4);
    v[0] = a.x; v[1] = a.y; v[2] = a.z; v[3] = a.w;
    v[4] = b.x; v[5] = b.y; v[6] = b.z; v[7] = b.w;
  } else if (k < H + 32) {
    const int e = (k - H) >> 3;
    const float* s = lora_B + ((size_t)active[e] * O + o) * 8;  // [E,O,r] r contig
    float4 a = *(const float4*)s, b = *(const float4*)(s + 4);
    v[0] = a.x; v[1] = a.y; v[2] = a.z; v[3] = a.w;
    v[4] = b.x; v[5] = b.y; v[6] = b.z; v[7] = b.w;
  } else {
#pragma unroll
    for (int i = 0; i < 8; ++i) v[i] = 0.f;
  }
  f16x8 h;
#pragma unroll
  for (int i = 0; i < 8; ++i) h[i] = (_Float16)v[i];
  *(f16x8*)(wh + (size_t)o * KP + k) = h;
}

// ---------------------------------------------------------------------------
// Kernel 3: xh[t][KP] fp16 = [ x[t][0..4095] | c[t][0..31] | 0 ]
// ---------------------------------------------------------------------------
__global__ __launch_bounds__(256) void convert_x_kernel(
    const float* __restrict__ x, const float* __restrict__ c,
    _Float16* __restrict__ xh) {
  const long t = blockIdx.x;
  const int tid = threadIdx.x;
#pragma unroll
  for (int i = 0; i < 4; ++i) {
    const int k = i * 1024 + tid * 4;
    float4 v = *(const float4*)(x + t * H + k);
    f16x4 h;
    h[0] = (_Float16)v.x; h[1] = (_Float16)v.y;
    h[2] = (_Float16)v.z; h[3] = (_Float16)v.w;
    *(f16x4*)(xh + t * KP + k) = h;
  }
  if (tid < 8) {
    const int j = tid * 4;
    float4 v = *(const float4*)(c + t * 32 + j);
    f16x4 h;
    h[0] = (_Float16)v.x; h[1] = (_Float16)v.y;
    h[2] = (_Float16)v.z; h[3] = (_Float16)v.w;
    *(f16x4*)(xh + t * KP + H + j) = h;
  } else if (tid < 16) {
    const int j = (tid - 8) * 4;
    *(unsigned long long*)(xh + t * KP + H + 32 + j) = 0ull;  // zero pad
  }
}

// ---------------------------------------------------------------------------
// Kernel 4: fp16 MFMA GEMM. out[t][o] = sum_k xh[t][k]*wh[o][k] + b_base[o].
// 128x128 tile, BK=64 (128B LDS rows), 4 waves each owning 64x64 (4x4 frags).
// Staging: global_load_lds dwordx4, source pre-swizzled slot^=(row&7) so the
// swizzled LDS layout gives conflict-free ds_read_b128 (2 lanes/bank = free).
// ---------------------------------------------------------------------------
constexpr int BM = 128, BN = 128, BK = 64;

__global__ __launch_bounds__(256) void gemm_kernel(
    const _Float16* __restrict__ xh, const _Float16* __restrict__ wh,
    const float* __restrict__ b_base, float* __restrict__ out) {
  __shared__ _Float16 As[BM * BK];  // [row][slot^ (row&7)] : row=128B=8 slots x 16B
  __shared__ _Float16 Ws[BN * BK];
  const int tid  = threadIdx.x;
  const int lane = tid & 63;
  const int wave = tid >> 6;
  const int im = (int)(blockIdx.x >> 5);   // 64 M-tiles
  const int in = (int)(blockIdx.x & 31);   // 32 N-tiles
  const size_t trow0 = (size_t)im * BM;
  const size_t ocol0 = (size_t)in * BN;
  const int wr = wave >> 1, wc = wave & 1; // wave sub-tile 64x64

  f32x4 acc[4][4];
  const f32x4 zero = {0.f, 0.f, 0.f, 0.f};
#pragma unroll
  for (int m = 0; m < 4; ++m)
#pragma unroll
    for (int n = 0; n < 4; ++n) acc[m][n] = zero;

  // staging lane constants: chunk = 8 rows x 128B; lane -> (row=l>>3, lds slot=l&7)
  const int srow  = lane >> 3;
  const int sslot = (lane & 7) ^ srow;     // pre-swizzled global slot
  const int r15 = lane & 15;
  const int kg  = lane >> 4;               // 0..3 k-group of the MFMA frag

  for (int step = 0; step < KP / BK; ++step) {   // 65 steps
    const int k0 = step * BK;
    __syncthreads();
#pragma unroll
    for (int i = 0; i < 8; ++i) {
      const int ch  = wave + 4 * i;        // 0..31 ; <16 = A region, else W
      const int sub = ch & 15;
      const int row = sub * 8 + srow;
      if (ch < 16)
        gload16(xh + (trow0 + row) * KP + k0 + sslot * 8, As + sub * 512);
      else
        gload16(wh + (ocol0 + row) * KP + k0 + sslot * 8, Ws + sub * 512);
    }
    __syncthreads();
#pragma unroll
    for (int kk = 0; kk < 2; ++kk) {
      f16x8 a[4], b[4];
#pragma unroll
      for (int m = 0; m < 4; ++m) {
        const int row  = wr * 64 + m * 16 + r15;
        const int slot = (kk * 4 + kg) ^ (row & 7);
        a[m] = *(const f16x8*)(As + row * 64 + slot * 8);
      }
#pragma unroll
      for (int n = 0; n < 4; ++n) {
        const int row  = wc * 64 + n * 16 + r15;
        const int slot = (kk * 4 + kg) ^ (row & 7);
        b[n] = *(const f16x8*)(Ws + row * 64 + slot * 8);
      }
#pragma unroll
      for (int m = 0; m < 4; ++m)
#pragma unroll
        for (int n = 0; n < 4; ++n)
          acc[m][n] = __builtin_amdgcn_mfma_f32_16x16x32_f16(a[m], b[n], acc[m][n], 0, 0, 0);
    }
  }
  // epilogue: C/D layout col=lane&15 (o), row=(lane>>4)*4+j (token)
#pragma unroll
  for (int n = 0; n < 4; ++n) {
    const size_t col = ocol0 + wc * 64 + n * 16 + r15;
    const float bb = b_base[col];
#pragma unroll
    for (int m = 0; m < 4; ++m) {
      const size_t row = trow0 + wr * 64 + m * 16 + kg * 4;
#pragma unroll
      for (int j = 0; j < 4; ++j)
        out[(row + j) * O + col] = acc[m][n][j] + bb;
    }
  }
}

// ---------------------------------------------------------------------------
extern "C" void kernel_launch(void* const* d_in, const int* in_sizes, int n_in,
                              void* d_out, int out_size, void* d_ws, size_t ws_size,
                              hipStream_t stream) {
  const float* x        = (const float*)d_in[0];
  const float* W_base   = (const float*)d_in[1];
  const float* b_base   = (const float*)d_in[2];
  const float* lora_A   = (const float*)d_in[3];
  const float* lora_B   = (const float*)d_in[4];
  const float* router_W = (const float*)d_in[5];
  const float* router_b = (const float*)d_in[6];
  const float* prior    = (const float*)d_in[7];
  const int*   active   = (const int*)d_in[8];
  float* out = (float*)d_out;

  const int M = in_sizes[0] / H;  // 8192 tokens

  char* ws = (char*)d_ws;
  float*    c  = (float*)ws;                                  // M*32*4   = 1 MB
  _Float16* xh = (_Float16*)(ws + (size_t)M * 32 * 4);        // M*KP*2   = 68.2 MB
  _Float16* wh = (_Float16*)(ws + (size_t)M * 32 * 4 + (size_t)M * KP * 2);  // 34.1 MB

  router_c_kernel<<<M / 32, 256, 0, stream>>>(x, lora_A, router_W, router_b,
                                              prior, active, c);
  convert_w_kernel<<<O * (KP / 8) / 256, 256, 0, stream>>>(W_base, lora_B, active, wh);
  convert_x_kernel<<<M, 256, 0, stream>>>(x, c, xh);
  gemm_kernel<<<(M / BM) * (O / BN), 256, 0, stream>>>(xh, wh, b_base, out);
}

// Round 2
// 580.054 us; speedup vs baseline: 1.5474x; 1.5474x over previous
//
#include <hip/hip_runtime.h>
#include <hip/hip_bf16.h>

// MultiExpertLoRALinear on MI355X.
// Round 2: router/z-path rebuilt as a fused MFMA kernel.
// Pipeline:
//   convert_w    : wh[o][KP] fp16 = [W_base | Bcat | 0], plus vh[48][H] fp16
//                  (rows 0..31 = lora_A[active] (e*8+r), 32..35 = router_W[active],
//                   36..47 = zeros).
//   router_fused : reads fp32 x, converts to fp16 in-register, writes xh main
//                  cols AND computes z[16 tok][48] = xh @ vh^T via MFMA
//                  (8 waves x 512-K-slices), LDS-reduces, does the softmax, and
//                  writes the 32 c-columns + 32 zero-pad cols of xh.
//   gemm         : single fp16 MFMA GEMM [M, O, KP=4160] = base + LoRA + router,
//                  epilogue adds bias. (Unchanged from round 1 — validated.)

typedef _Float16 f16x8 __attribute__((ext_vector_type(8)));
typedef _Float16 f16x4 __attribute__((ext_vector_type(4)));
typedef float    f32x4 __attribute__((ext_vector_type(4)));

constexpr int H  = 4096;
constexpr int O  = 4096;
constexpr int KP = 4160;   // 4096 + 32 (c cols) + 32 zero pad
constexpr int EA = 4;
constexpr float SCALING_F = 2.0f;  // alpha/rank

typedef const __attribute__((address_space(1))) void gvoid;
typedef __attribute__((address_space(3))) void svoid;

__device__ inline void gload16(const void* g, void* s) {
  __builtin_amdgcn_global_load_lds((gvoid*)g, (svoid*)s, 16, 0, 0);
}

// ---------------------------------------------------------------------------
// Kernel 1: build wh (W_base | Bcat | 0) and vh (lora_A | router_W | 0), fp16.
// ---------------------------------------------------------------------------
constexpr int WH_GROUPS = O * (KP / 8);        // 4096*520
constexpr int VH_GROUPS = 48 * (H / 8);        // 48*512

__global__ __launch_bounds__(256) void convert_w_kernel(
    const float* __restrict__ W, const float* __restrict__ lora_B,
    const float* __restrict__ lora_A, const float* __restrict__ router_W,
    const int* __restrict__ active, _Float16* __restrict__ wh,
    _Float16* __restrict__ vh) {
  const int g = blockIdx.x * 256 + threadIdx.x;
  float v[8];
  _Float16* dst;
  if (g < WH_GROUPS) {
    const int o = g / 520;
    const int k = (g % 520) * 8;
    dst = wh + (size_t)o * KP + k;
    if (k < H) {
      const float* s = W + (size_t)o * H + k;
      float4 a = *(const float4*)s, b = *(const float4*)(s + 4);
      v[0] = a.x; v[1] = a.y; v[2] = a.z; v[3] = a.w;
      v[4] = b.x; v[5] = b.y; v[6] = b.z; v[7] = b.w;
    } else if (k < H + 32) {
      const int e = (k - H) >> 3;
      const float* s = lora_B + ((size_t)active[e] * O + o) * 8;  // [E,O,r]
      float4 a = *(const float4*)s, b = *(const float4*)(s + 4);
      v[0] = a.x; v[1] = a.y; v[2] = a.z; v[3] = a.w;
      v[4] = b.x; v[5] = b.y; v[6] = b.z; v[7] = b.w;
    } else {
#pragma unroll
      for (int i = 0; i < 8; ++i) v[i] = 0.f;
    }
  } else {
    const int gg = g - WH_GROUPS;
    if (gg >= VH_GROUPS) return;
    const int j  = gg >> 9;          // 0..47
    const int k  = (gg & 511) * 8;
    dst = vh + (size_t)j * H + k;
    const float* s = nullptr;
    if (j < 32)       s = lora_A + (size_t)(active[j >> 3] * 8 + (j & 7)) * H + k;
    else if (j < 36)  s = router_W + (size_t)active[j - 32] * H + k;
    if (s) {
      float4 a = *(const float4*)s, b = *(const float4*)(s + 4);
      v[0] = a.x; v[1] = a.y; v[2] = a.z; v[3] = a.w;
      v[4] = b.x; v[5] = b.y; v[6] = b.z; v[7] = b.w;
    } else {
#pragma unroll
      for (int i = 0; i < 8; ++i) v[i] = 0.f;
    }
  }
  f16x8 h;
#pragma unroll
  for (int i = 0; i < 8; ++i) h[i] = (_Float16)v[i];
  *(f16x8*)dst = h;
}

// ---------------------------------------------------------------------------
// Kernel 2: fused convert_x + router + c-columns.
// Block: 512 threads = 8 waves, 16 tokens, each wave a 512-wide K-slice.
// Per wave K-step(32): load x fp32 (2xfloat4), cvt->f16x8, store xh frag,
// 3x mfma_16x16x32_f16 against vh rows (j = nf*16 + lane&15).
// Then LDS reduce over waves, softmax over the 4 active experts, write
// c[32] fp16 + zero-pad into xh cols 4096..4159.
// ---------------------------------------------------------------------------
constexpr int RT = 16;    // tokens per block
constexpr int RW = 8;     // waves per block
constexpr int KSL = H / RW;  // 512

__global__ __launch_bounds__(512) void router_fused_kernel(
    const float* __restrict__ x, const _Float16* __restrict__ vh,
    const float* __restrict__ router_b, const float* __restrict__ prior,
    const int* __restrict__ active, _Float16* __restrict__ xh) {
  __shared__ float zred[RW][RT][48];
  const int tid  = threadIdx.x;
  const int lane = tid & 63;
  const int w    = tid >> 6;
  const long t0  = (long)blockIdx.x * RT;
  const int r15  = lane & 15;
  const int kg   = lane >> 4;
  const long row = t0 + r15;

  f32x4 acc[3];
  const f32x4 zero = {0.f, 0.f, 0.f, 0.f};
  acc[0] = zero; acc[1] = zero; acc[2] = zero;

  const float*    xp  = x  + row * H  + w * KSL + kg * 8;
  _Float16*       xhp = xh + row * KP + w * KSL + kg * 8;
  const _Float16* vp  = vh + (size_t)r15 * H + w * KSL + kg * 8;

#pragma unroll 4
  for (int s = 0; s < KSL / 32; ++s) {
    const int ko = s * 32;
    float4 v0 = *(const float4*)(xp + ko);
    float4 v1 = *(const float4*)(xp + ko + 4);
    f16x8 a;
    a[0] = (_Float16)v0.x; a[1] = (_Float16)v0.y;
    a[2] = (_Float16)v0.z; a[3] = (_Float16)v0.w;
    a[4] = (_Float16)v1.x; a[5] = (_Float16)v1.y;
    a[6] = (_Float16)v1.z; a[7] = (_Float16)v1.w;
    *(f16x8*)(xhp + ko) = a;
#pragma unroll
    for (int nf = 0; nf < 3; ++nf) {
      f16x8 b = *(const f16x8*)(vp + (size_t)nf * 16 * H + ko);
      acc[nf] = __builtin_amdgcn_mfma_f32_16x16x32_f16(a, b, acc[nf], 0, 0, 0);
    }
  }

  // scatter partial z into LDS: C/D layout col=lane&15 (j), row=(lane>>4)*4+r (tok)
#pragma unroll
  for (int nf = 0; nf < 3; ++nf)
#pragma unroll
    for (int r = 0; r < 4; ++r)
      zred[w][kg * 4 + r][nf * 16 + r15] = acc[nf][r];
  __syncthreads();

  // reduce over the 8 waves: 768 slots, 512 threads -> <=2 slots each
  float s0 = 0.f, s1 = 0.f;
  {
    const int a0 = tid;            // < 768
    if (a0 < RT * 48) {
      const int t = a0 / 48, j = a0 % 48;
#pragma unroll
      for (int ww = 0; ww < RW; ++ww) s0 += zred[ww][t][j];
    }
    const int a1 = tid + 512;
    if (a1 < RT * 48) {
      const int t = a1 / 48, j = a1 % 48;
#pragma unroll
      for (int ww = 0; ww < RW; ++ww) s1 += zred[ww][t][j];
    }
  }
  __syncthreads();
  if (tid < RT * 48) zred[0][tid / 48][tid % 48] = s0;
  if (tid + 512 < RT * 48) zred[0][(tid + 512) / 48][(tid + 512) % 48] = s1;
  __syncthreads();

  // softmax + c-columns: thread = (token t, expert e)
  if (tid < RT * EA) {
    const int t = tid >> 2, e = tid & 3;
    const float* zt = &zred[0][t][0];
    float le[EA], mx = -1e30f;
#pragma unroll
    for (int e2 = 0; e2 < EA; ++e2) {
      const int ae = active[e2];
      le[e2] = logf(prior[ae] + 1e-12f) + zt[32 + e2] + router_b[ae];
      mx = fmaxf(mx, le[e2]);
    }
    float sum = 0.f;
#pragma unroll
    for (int e2 = 0; e2 < EA; ++e2) sum += expf(le[e2] - mx);
    const float a = expf(le[e] - mx) / sum * SCALING_F;
    f16x8 ch;
#pragma unroll
    for (int r = 0; r < 8; ++r) ch[r] = (_Float16)(a * zt[e * 8 + r]);
    _Float16* xr = xh + (t0 + t) * KP + H;
    *(f16x8*)(xr + e * 8) = ch;
    // zero pad cols 4128..4159 (16B per thread)
    f16x8 zz;
#pragma unroll
    for (int r = 0; r < 8; ++r) zz[r] = (_Float16)0.f;
    *(f16x8*)(xr + 32 + e * 8) = zz;
  }
}

// ---------------------------------------------------------------------------
// Kernel 3: fp16 MFMA GEMM. out[t][o] = sum_k xh[t][k]*wh[o][k] + b_base[o].
// 128x128 tile, BK=64 (128B LDS rows), 4 waves each owning 64x64 (4x4 frags).
// global_load_lds dwordx4 staging, source pre-swizzled slot^=(row&7) so the
// swizzled LDS layout gives conflict-free ds_read_b128.
// ---------------------------------------------------------------------------
constexpr int BM = 128, BN = 128, BK = 64;

__global__ __launch_bounds__(256) void gemm_kernel(
    const _Float16* __restrict__ xh, const _Float16* __restrict__ wh,
    const float* __restrict__ b_base, float* __restrict__ out) {
  __shared__ _Float16 As[BM * BK];
  __shared__ _Float16 Ws[BN * BK];
  const int tid  = threadIdx.x;
  const int lane = tid & 63;
  const int wave = tid >> 6;
  const int im = (int)(blockIdx.x >> 5);
  const int in = (int)(blockIdx.x & 31);
  const size_t trow0 = (size_t)im * BM;
  const size_t ocol0 = (size_t)in * BN;
  const int wr = wave >> 1, wc = wave & 1;

  f32x4 acc[4][4];
  const f32x4 zero = {0.f, 0.f, 0.f, 0.f};
#pragma unroll
  for (int m = 0; m < 4; ++m)
#pragma unroll
    for (int n = 0; n < 4; ++n) acc[m][n] = zero;

  const int srow  = lane >> 3;
  const int sslot = (lane & 7) ^ srow;
  const int r15 = lane & 15;
  const int kg  = lane >> 4;

  for (int step = 0; step < KP / BK; ++step) {
    const int k0 = step * BK;
    __syncthreads();
#pragma unroll
    for (int i = 0; i < 8; ++i) {
      const int ch  = wave + 4 * i;
      const int sub = ch & 15;
      const int row = sub * 8 + srow;
      if (ch < 16)
        gload16(xh + (trow0 + row) * KP + k0 + sslot * 8, As + sub * 512);
      else
        gload16(wh + (ocol0 + row) * KP + k0 + sslot * 8, Ws + sub * 512);
    }
    __syncthreads();
#pragma unroll
    for (int kk = 0; kk < 2; ++kk) {
      f16x8 a[4], b[4];
#pragma unroll
      for (int m = 0; m < 4; ++m) {
        const int row  = wr * 64 + m * 16 + r15;
        const int slot = (kk * 4 + kg) ^ (row & 7);
        a[m] = *(const f16x8*)(As + row * 64 + slot * 8);
      }
#pragma unroll
      for (int n = 0; n < 4; ++n) {
        const int row  = wc * 64 + n * 16 + r15;
        const int slot = (kk * 4 + kg) ^ (row & 7);
        b[n] = *(const f16x8*)(Ws + row * 64 + slot * 8);
      }
#pragma unroll
      for (int m = 0; m < 4; ++m)
#pragma unroll
        for (int n = 0; n < 4; ++n)
          acc[m][n] = __builtin_amdgcn_mfma_f32_16x16x32_f16(a[m], b[n], acc[m][n], 0, 0, 0);
    }
  }
#pragma unroll
  for (int n = 0; n < 4; ++n) {
    const size_t col = ocol0 + wc * 64 + n * 16 + r15;
    const float bb = b_base[col];
#pragma unroll
    for (int m = 0; m < 4; ++m) {
      const size_t row = trow0 + wr * 64 + m * 16 + kg * 4;
#pragma unroll
      for (int j = 0; j < 4; ++j)
        out[(row + j) * O + col] = acc[m][n][j] + bb;
    }
  }
}

// ---------------------------------------------------------------------------
extern "C" void kernel_launch(void* const* d_in, const int* in_sizes, int n_in,
                              void* d_out, int out_size, void* d_ws, size_t ws_size,
                              hipStream_t stream) {
  const float* x        = (const float*)d_in[0];
  const float* W_base   = (const float*)d_in[1];
  const float* b_base   = (const float*)d_in[2];
  const float* lora_A   = (const float*)d_in[3];
  const float* lora_B   = (const float*)d_in[4];
  const float* router_W = (const float*)d_in[5];
  const float* router_b = (const float*)d_in[6];
  const float* prior    = (const float*)d_in[7];
  const int*   active   = (const int*)d_in[8];
  float* out = (float*)d_out;

  const int M = in_sizes[0] / H;  // 8192 tokens

  char* ws = (char*)d_ws;
  _Float16* xh = (_Float16*)ws;                               // M*KP*2  = 68.2 MB
  _Float16* wh = (_Float16*)(ws + (size_t)M * KP * 2);        // O*KP*2  = 34.1 MB
  _Float16* vh = (_Float16*)(ws + (size_t)M * KP * 2 + (size_t)O * KP * 2);  // 384 KB

  const int cw_grid = (WH_GROUPS + VH_GROUPS + 255) / 256;
  convert_w_kernel<<<cw_grid, 256, 0, stream>>>(W_base, lora_B, lora_A, router_W,
                                                active, wh, vh);
  router_fused_kernel<<<M / RT, 512, 0, stream>>>(x, vh, router_b, prior, active, xh);
  gemm_kernel<<<(M / BM) * (O / BN), 256, 0, stream>>>(xh, wh, b_base, out);
}